// Round 14
// baseline (54.570 us; speedup 1.0000x reference)
//
#include <hip/hip_runtime.h>

constexpr int IMG_H = 2048;
constexpr int IMG_W = 2048;
constexpr int P = 4;     // output rows per thread
constexpr int REPS = 3;  // diagnostic: repeat body to make kernel PMC-visible

// compare-exchange: a=min, b=max (2 VALU)
#define CE(a, b) {                                              \
    float _mn, _mx;                                             \
    asm("v_min_f32 %0, %1, %2" : "=v"(_mn) : "v"(a), "v"(b));   \
    asm("v_max_f32 %0, %1, %2" : "=v"(_mx) : "v"(a), "v"(b));   \
    a = _mn; b = _mx;                                           \
}

// 3-element sort via VOP3 3-input ops: a=min, b=med, c=max (3 VALU)
#define SORT3(a, b, c) {                                                      \
    float _n, _d, _x;                                                         \
    asm("v_min3_f32 %0, %1, %2, %3" : "=v"(_n) : "v"(a), "v"(b), "v"(c));     \
    asm("v_med3_f32 %0, %1, %2, %3" : "=v"(_d) : "v"(a), "v"(b), "v"(c));     \
    asm("v_max3_f32 %0, %1, %2, %3" : "=v"(_x) : "v"(a), "v"(b), "v"(c));     \
    a = _n; b = _d; c = _x;                                                   \
}

__device__ __forceinline__ void sw14(float& a0, float& a1, float& a2, float& a3, float& a4,
                                     float& a5, float& a6, float& a7, float& a8, float& a9,
                                     float& a10, float& a11, float& a12, float& a13) {
    SORT3(a0, a1, a2) SORT3(a3, a4, a5) SORT3(a6, a7, a8) SORT3(a9, a10, a11) CE(a12, a13)
    SORT3(a0, a3, a6) SORT3(a0, a9, a12)
    SORT3(a2, a5, a8) SORT3(a8, a11, a13)
}
__device__ __forceinline__ void sw13(float& a0, float& a1, float& a2, float& a3, float& a4,
                                     float& a5, float& a6, float& a7, float& a8, float& a9,
                                     float& a10, float& a11, float& a12) {
    SORT3(a0, a1, a2) SORT3(a3, a4, a5) SORT3(a6, a7, a8) SORT3(a9, a10, a11)
    SORT3(a0, a3, a6) SORT3(a0, a9, a12)
    SORT3(a2, a5, a8) SORT3(a8, a11, a12)
}
__device__ __forceinline__ void sw12(float& a0, float& a1, float& a2, float& a3, float& a4,
                                     float& a5, float& a6, float& a7, float& a8, float& a9,
                                     float& a10, float& a11) {
    SORT3(a0, a1, a2) SORT3(a3, a4, a5) SORT3(a6, a7, a8) SORT3(a9, a10, a11)
    SORT3(a0, a3, a6) CE(a0, a9)
    SORT3(a2, a5, a8) CE(a8, a11)
}
__device__ __forceinline__ void sw11(float& a0, float& a1, float& a2, float& a3, float& a4,
                                     float& a5, float& a6, float& a7, float& a8, float& a9,
                                     float& a10) {
    SORT3(a0, a1, a2) SORT3(a3, a4, a5) SORT3(a6, a7, a8) CE(a9, a10)
    SORT3(a0, a3, a6) CE(a0, a9)
    SORT3(a2, a5, a8) CE(a8, a10)
}
__device__ __forceinline__ void sw10(float& a0, float& a1, float& a2, float& a3, float& a4,
                                     float& a5, float& a6, float& a7, float& a8, float& a9) {
    SORT3(a0, a1, a2) SORT3(a3, a4, a5) SORT3(a6, a7, a8)
    SORT3(a0, a3, a6) CE(a0, a9)
    SORT3(a2, a5, a8) CE(a8, a9)
}
__device__ __forceinline__ void sw9(float& a0, float& a1, float& a2, float& a3, float& a4,
                                    float& a5, float& a6, float& a7, float& a8) {
    SORT3(a0, a1, a2) SORT3(a3, a4, a5) SORT3(a6, a7, a8)
    SORT3(a0, a3, a6)
    SORT3(a2, a5, a8)
}
__device__ __forceinline__ void sw8(float& a0, float& a1, float& a2, float& a3, float& a4,
                                    float& a5, float& a6, float& a7) {
    SORT3(a0, a1, a2) SORT3(a3, a4, a5) CE(a6, a7)
    SORT3(a0, a3, a6)
    SORT3(a2, a5, a7)
}
__device__ __forceinline__ void sw7(float& a0, float& a1, float& a2, float& a3, float& a4,
                                    float& a5, float& a6) {
    SORT3(a0, a1, a2) SORT3(a3, a4, a5)
    SORT3(a0, a3, a6)
    SORT3(a2, a5, a6)
}
__device__ __forceinline__ void sw6(float& a0, float& a1, float& a2, float& a3, float& a4,
                                    float& a5) {
    SORT3(a0, a1, a2) SORT3(a3, a4, a5)
    CE(a0, a3)
    CE(a2, a5)
}

__device__ __forceinline__ float med5(float l0, float l1, float l2, float l3, float l4) {
    CE(l0, l1) CE(l2, l3)
    float a, b;
    asm("v_max_f32 %0, %1, %2" : "=v"(a) : "v"(l0), "v"(l2));
    asm("v_min_f32 %0, %1, %2" : "=v"(b) : "v"(l1), "v"(l3));
    return __builtin_amdgcn_fmed3f(a, b, l4);
}

__device__ __forceinline__ float tail5(float l1, float l2, float l3, float l4, float l5,
                                       float l6, float l7, float l8,
                                       float p0, float p1, float p2, float p3, float p4) {
    float l0 = p0;
    sw9(l0, l1, l2, l3, l4, l5, l6, l7, l8);
    l0 = p1;
    sw8(l0, l1, l2, l3, l4, l5, l6, l7);
    l0 = p2;
    sw7(l0, l1, l2, l3, l4, l5, l6);
    l0 = p3;
    sw6(l0, l1, l2, l3, l4, l5);
    l0 = p4;
    return med5(l0, l1, l2, l3, l4);
}

__device__ __forceinline__ void shared20(float s0, float s1, float s2, float s3, float s4,
                                         float s5, float s6, float s7, float s8, float s9,
                                         float s10, float s11, float s12, float s13,
                                         float s14, float s15, float s16, float s17,
                                         float s18, float s19,
                                         float& o0, float& o1, float& o2, float& o3,
                                         float& o4, float& o5, float& o6, float& o7) {
    sw14(s0, s1, s2, s3, s4, s5, s6, s7, s8, s9, s10, s11, s12, s13);
    s0 = s14;
    sw13(s0, s1, s2, s3, s4, s5, s6, s7, s8, s9, s10, s11, s12);
    s0 = s15;
    sw12(s0, s1, s2, s3, s4, s5, s6, s7, s8, s9, s10, s11);
    s0 = s16;
    sw11(s0, s1, s2, s3, s4, s5, s6, s7, s8, s9, s10);
    s0 = s17;
    sw10(s0, s1, s2, s3, s4, s5, s6, s7, s8, s9);
    s0 = s18;
    sw9(s0, s1, s2, s3, s4, s5, s6, s7, s8);
    s0 = s19;
    o0 = s0; o1 = s1; o2 = s2; o3 = s3; o4 = s4; o5 = s5; o6 = s6; o7 = s7;
}

__device__ __forceinline__ int rowbase(int r) {
    r = (r < 0) ? -r : r;
    r = (r >= IMG_H) ? 2 * IMG_H - 2 - r : r;
    return r * IMG_W;
}

#define LOADR(R, rb) {                                        \
    const int _b = (rb);                                      \
    R##0 = img[_b + c0]; R##1 = img[_b + c1];                 \
    R##2 = img[_b + c2]; R##3 = img[_b + c3];                 \
    R##4 = img[_b + c4]; R##5 = img[_b + c5];                 \
}

#define STEP(Ra, Rb, Rc, Rd, Re, Rf, yy) {                                     \
    LOADR(Rf, rowbase((yy) + 3))                                               \
    float u0, u1, u2, u3, u4, u5, u6, u7;                                      \
    shared20(Ra##1, Ra##2, Ra##3, Ra##4, Rb##1, Rb##2, Rb##3, Rb##4,           \
             Rc##1, Rc##2, Rc##3, Rc##4, Rd##1, Rd##2, Rd##3, Rd##4,           \
             Re##1, Re##2, Re##3, Re##4, u0, u1, u2, u3, u4, u5, u6, u7);      \
    const float _mL = tail5(u0, u1, u2, u3, u4, u5, u6, u7,                    \
                            Ra##0, Rb##0, Rc##0, Rd##0, Re##0);                \
    const float _mR = tail5(u0, u1, u2, u3, u4, u5, u6, u7,                    \
                            Ra##5, Rb##5, Rc##5, Rd##5, Re##5);                \
    *reinterpret_cast<float2*>(out + (yy) * IMG_W + xL) = make_float2(_mL, _mR); \
}

__global__ __launch_bounds__(256) void median5x5_strip(const float* __restrict__ img,
                                                       float* __restrict__ out) {
    const int t = blockIdx.x * blockDim.x + threadIdx.x;      // pair-column 0..1023
    const int strip = blockIdx.y * blockDim.y + threadIdx.y;  // 0..511
    const int xL = 2 * t;

    // reflected column indices xL-2 .. xL+3 (constant over the strip)
    int c0 = xL - 2, c1 = xL - 1, c4 = xL + 2, c5 = xL + 3;
    c0 = (c0 < 0) ? -c0 : c0;
    c1 = (c1 < 0) ? -c1 : c1;
    c4 = (c4 >= IMG_W) ? 2 * IMG_W - 2 - c4 : c4;
    c5 = (c5 >= IMG_W) ? 2 * IMG_W - 2 - c5 : c5;
    const int c2 = xL, c3 = xL + 1;

    // DIAGNOSTIC: repeat the entire body REPS times (idempotent — identical
    // stores each rep). rofs is 0 at runtime but opaque to the compiler and
    // rep-dependent, defeating cross-rep CSE/LICM so every rep re-executes.
#pragma unroll 1
    for (int rep = 0; rep < REPS; ++rep) {
        int rofs = rep;
        asm("" : "+v"(rofs));
        rofs -= rep;  // runtime 0, compile-time unknown

        const int y0 = strip * P + rofs;

        float A0, A1, A2, A3, A4, A5;
        float B0, B1, B2, B3, B4, B5;
        float C0, C1, C2, C3, C4, C5;
        float D0, D1, D2, D3, D4, D5;
        float E0, E1, E2, E3, E4, E5;
        float F0, F1, F2, F3, F4, F5;

        LOADR(A, rowbase(y0 - 2))
        LOADR(B, rowbase(y0 - 1))
        LOADR(C, rowbase(y0))
        LOADR(D, rowbase(y0 + 1))
        LOADR(E, rowbase(y0 + 2))

        STEP(A, B, C, D, E, F, y0 + 0)
        STEP(B, C, D, E, F, A, y0 + 1)
        STEP(C, D, E, F, A, B, y0 + 2)
        STEP(D, E, F, A, B, C, y0 + 3)
    }
}

extern "C" void kernel_launch(void* const* d_in, const int* in_sizes, int n_in,
                              void* d_out, int out_size, void* d_ws, size_t ws_size,
                              hipStream_t stream) {
    const float* img = (const float*)d_in[0];
    float* out = (float*)d_out;
    dim3 block(64, 4);
    dim3 grid((IMG_W / 2) / 64, IMG_H / P / 4);   // 16 x 128 = 2048 blocks
    median5x5_strip<<<grid, block, 0, stream>>>(img, out);
}

// Round 15
// 22.508 us; speedup vs baseline: 2.4245x; 2.4245x over previous
//
#include <hip/hip_runtime.h>

constexpr int IMG_H = 2048;
constexpr int IMG_W = 2048;
constexpr int P = 8;  // output rows per thread

// compare-exchange: a=min, b=max (2 VALU)
#define CE(a, b) {                                              \
    float _mn, _mx;                                             \
    asm("v_min_f32 %0, %1, %2" : "=v"(_mn) : "v"(a), "v"(b));   \
    asm("v_max_f32 %0, %1, %2" : "=v"(_mx) : "v"(a), "v"(b));   \
    a = _mn; b = _mx;                                           \
}

// 3-element sort via VOP3 3-input ops: a=min, b=med, c=max (3 VALU)
#define SORT3(a, b, c) {                                                      \
    float _n, _d, _x;                                                         \
    asm("v_min3_f32 %0, %1, %2, %3" : "=v"(_n) : "v"(a), "v"(b), "v"(c));     \
    asm("v_med3_f32 %0, %1, %2, %3" : "=v"(_d) : "v"(a), "v"(b), "v"(c));     \
    asm("v_max3_f32 %0, %1, %2, %3" : "=v"(_x) : "v"(a), "v"(b), "v"(c));     \
    a = _n; b = _d; c = _x;                                                   \
}

__device__ __forceinline__ void sw14(float& a0, float& a1, float& a2, float& a3, float& a4,
                                     float& a5, float& a6, float& a7, float& a8, float& a9,
                                     float& a10, float& a11, float& a12, float& a13) {
    SORT3(a0, a1, a2) SORT3(a3, a4, a5) SORT3(a6, a7, a8) SORT3(a9, a10, a11) CE(a12, a13)
    SORT3(a0, a3, a6) SORT3(a0, a9, a12)
    SORT3(a2, a5, a8) SORT3(a8, a11, a13)
}
__device__ __forceinline__ void sw13(float& a0, float& a1, float& a2, float& a3, float& a4,
                                     float& a5, float& a6, float& a7, float& a8, float& a9,
                                     float& a10, float& a11, float& a12) {
    SORT3(a0, a1, a2) SORT3(a3, a4, a5) SORT3(a6, a7, a8) SORT3(a9, a10, a11)
    SORT3(a0, a3, a6) SORT3(a0, a9, a12)
    SORT3(a2, a5, a8) SORT3(a8, a11, a12)
}
__device__ __forceinline__ void sw12(float& a0, float& a1, float& a2, float& a3, float& a4,
                                     float& a5, float& a6, float& a7, float& a8, float& a9,
                                     float& a10, float& a11) {
    SORT3(a0, a1, a2) SORT3(a3, a4, a5) SORT3(a6, a7, a8) SORT3(a9, a10, a11)
    SORT3(a0, a3, a6) CE(a0, a9)
    SORT3(a2, a5, a8) CE(a8, a11)
}
__device__ __forceinline__ void sw11(float& a0, float& a1, float& a2, float& a3, float& a4,
                                     float& a5, float& a6, float& a7, float& a8, float& a9,
                                     float& a10) {
    SORT3(a0, a1, a2) SORT3(a3, a4, a5) SORT3(a6, a7, a8) CE(a9, a10)
    SORT3(a0, a3, a6) CE(a0, a9)
    SORT3(a2, a5, a8) CE(a8, a10)
}
__device__ __forceinline__ void sw10(float& a0, float& a1, float& a2, float& a3, float& a4,
                                     float& a5, float& a6, float& a7, float& a8, float& a9) {
    SORT3(a0, a1, a2) SORT3(a3, a4, a5) SORT3(a6, a7, a8)
    SORT3(a0, a3, a6) CE(a0, a9)
    SORT3(a2, a5, a8) CE(a8, a9)
}
__device__ __forceinline__ void sw9(float& a0, float& a1, float& a2, float& a3, float& a4,
                                    float& a5, float& a6, float& a7, float& a8) {
    SORT3(a0, a1, a2) SORT3(a3, a4, a5) SORT3(a6, a7, a8)
    SORT3(a0, a3, a6)
    SORT3(a2, a5, a8)
}
__device__ __forceinline__ void sw8(float& a0, float& a1, float& a2, float& a3, float& a4,
                                    float& a5, float& a6, float& a7) {
    SORT3(a0, a1, a2) SORT3(a3, a4, a5) CE(a6, a7)
    SORT3(a0, a3, a6)
    SORT3(a2, a5, a7)
}
__device__ __forceinline__ void sw7(float& a0, float& a1, float& a2, float& a3, float& a4,
                                    float& a5, float& a6) {
    SORT3(a0, a1, a2) SORT3(a3, a4, a5)
    SORT3(a0, a3, a6)
    SORT3(a2, a5, a6)
}
__device__ __forceinline__ void sw6(float& a0, float& a1, float& a2, float& a3, float& a4,
                                    float& a5) {
    SORT3(a0, a1, a2) SORT3(a3, a4, a5)
    CE(a0, a3)
    CE(a2, a5)
}

__device__ __forceinline__ float med5(float l0, float l1, float l2, float l3, float l4) {
    CE(l0, l1) CE(l2, l3)
    float a, b;
    asm("v_max_f32 %0, %1, %2" : "=v"(a) : "v"(l0), "v"(l2));
    asm("v_min_f32 %0, %1, %2" : "=v"(b) : "v"(l1), "v"(l3));
    return __builtin_amdgcn_fmed3f(a, b, l4);
}

// tail: 8 shared survivors + 5 private column values -> exact median of 25
__device__ __forceinline__ float tail5(float l1, float l2, float l3, float l4, float l5,
                                       float l6, float l7, float l8,
                                       float p0, float p1, float p2, float p3, float p4) {
    float l0 = p0;
    sw9(l0, l1, l2, l3, l4, l5, l6, l7, l8);
    l0 = p1;
    sw8(l0, l1, l2, l3, l4, l5, l6, l7);
    l0 = p2;
    sw7(l0, l1, l2, l3, l4, l5, l6);
    l0 = p3;
    sw6(l0, l1, l2, l3, l4, l5);
    l0 = p4;
    return med5(l0, l1, l2, l3, l4);
}

// shared forgetful phase over 20 elements (4 shared cols x 5 rows) -> middle 8.
__device__ __forceinline__ void shared20(float s0, float s1, float s2, float s3, float s4,
                                         float s5, float s6, float s7, float s8, float s9,
                                         float s10, float s11, float s12, float s13,
                                         float s14, float s15, float s16, float s17,
                                         float s18, float s19,
                                         float& o0, float& o1, float& o2, float& o3,
                                         float& o4, float& o5, float& o6, float& o7) {
    sw14(s0, s1, s2, s3, s4, s5, s6, s7, s8, s9, s10, s11, s12, s13);
    s0 = s14;
    sw13(s0, s1, s2, s3, s4, s5, s6, s7, s8, s9, s10, s11, s12);
    s0 = s15;
    sw12(s0, s1, s2, s3, s4, s5, s6, s7, s8, s9, s10, s11);
    s0 = s16;
    sw11(s0, s1, s2, s3, s4, s5, s6, s7, s8, s9, s10);
    s0 = s17;
    sw10(s0, s1, s2, s3, s4, s5, s6, s7, s8, s9);
    s0 = s18;
    sw9(s0, s1, s2, s3, s4, s5, s6, s7, s8);
    s0 = s19;
    o0 = s0; o1 = s1; o2 = s2; o3 = s3; o4 = s4; o5 = s5; o6 = s6; o7 = s7;
}

__device__ __forceinline__ int rowbase(int r) {
    r = (r < 0) ? -r : r;
    r = (r >= IMG_H) ? 2 * IMG_H - 2 - r : r;
    return r * IMG_W;
}

// load one window row (6 reflected columns) into named registers R0..R5
#define LOADR(R, rb) {                                        \
    const int _b = (rb);                                      \
    R##0 = img[_b + c0]; R##1 = img[_b + c1];                 \
    R##2 = img[_b + c2]; R##3 = img[_b + c3];                 \
    R##4 = img[_b + c4]; R##5 = img[_b + c5];                 \
}

// compute + store one output row from 5 row buffers
#define COMPUTE(Ra, Rb, Rc, Rd, Re, yy) {                                      \
    float u0, u1, u2, u3, u4, u5, u6, u7;                                      \
    shared20(Ra##1, Ra##2, Ra##3, Ra##4, Rb##1, Rb##2, Rb##3, Rb##4,           \
             Rc##1, Rc##2, Rc##3, Rc##4, Rd##1, Rd##2, Rd##3, Rd##4,           \
             Re##1, Re##2, Re##3, Re##4, u0, u1, u2, u3, u4, u5, u6, u7);      \
    const float _mL = tail5(u0, u1, u2, u3, u4, u5, u6, u7,                    \
                            Ra##0, Rb##0, Rc##0, Rd##0, Re##0);                \
    const float _mR = tail5(u0, u1, u2, u3, u4, u5, u6, u7,                    \
                            Ra##5, Rb##5, Rc##5, Rd##5, Re##5);                \
    *reinterpret_cast<float2*>(out + (yy) * IMG_W + xL) = make_float2(_mL, _mR); \
}

// step with 2-ahead prefetch: issue load of row (yy)+4 into Rf, then compute row yy
#define STEPL(Rf, Ra, Rb, Rc, Rd, Re, yy) {                                    \
    LOADR(Rf, rowbase((yy) + 4))                                               \
    COMPUTE(Ra, Rb, Rc, Rd, Re, yy)                                            \
}
// step without prefetch (strip epilogue)
#define STEPN(Ra, Rb, Rc, Rd, Re, yy) COMPUTE(Ra, Rb, Rc, Rd, Re, yy)

__global__ __launch_bounds__(256) void median5x5_strip(const float* __restrict__ img,
                                                       float* __restrict__ out) {
    const int t = blockIdx.x * blockDim.x + threadIdx.x;      // pair-column 0..1023
    const int strip = blockIdx.y * blockDim.y + threadIdx.y;  // 0..255
    const int y0 = strip * P;
    const int xL = 2 * t;

    // reflected column indices xL-2 .. xL+3 (constant over the strip)
    int c0 = xL - 2, c1 = xL - 1, c4 = xL + 2, c5 = xL + 3;
    c0 = (c0 < 0) ? -c0 : c0;
    c1 = (c1 < 0) ? -c1 : c1;
    c4 = (c4 >= IMG_W) ? 2 * IMG_W - 2 - c4 : c4;
    c5 = (c5 >= IMG_W) ? 2 * IMG_W - 2 - c5 : c5;
    const int c2 = xL, c3 = xL + 1;

    // 7 row buffers: 5 in use + 2 in flight (2-step prefetch distance)
    float A0, A1, A2, A3, A4, A5;
    float B0, B1, B2, B3, B4, B5;
    float C0, C1, C2, C3, C4, C5;
    float D0, D1, D2, D3, D4, D5;
    float E0, E1, E2, E3, E4, E5;
    float F0, F1, F2, F3, F4, F5;
    float G0, G1, G2, G3, G4, G5;

    // prologue: rows y0-2 .. y0+3 (one row ahead already)
    LOADR(A, rowbase(y0 - 2))
    LOADR(B, rowbase(y0 - 1))
    LOADR(C, rowbase(y0))
    LOADR(D, rowbase(y0 + 1))
    LOADR(E, rowbase(y0 + 2))
    LOADR(F, rowbase(y0 + 3))

    STEPL(G, A, B, C, D, E, y0 + 0)   // prefetch y0+4
    STEPL(A, B, C, D, E, F, y0 + 1)   // prefetch y0+5
    STEPL(B, C, D, E, F, G, y0 + 2)   // prefetch y0+6
    STEPL(C, D, E, F, G, A, y0 + 3)   // prefetch y0+7
    STEPL(D, E, F, G, A, B, y0 + 4)   // prefetch y0+8
    STEPL(E, F, G, A, B, C, y0 + 5)   // prefetch y0+9
    STEPN(G, A, B, C, D, y0 + 6)
    STEPN(A, B, C, D, E, y0 + 7)
}

extern "C" void kernel_launch(void* const* d_in, const int* in_sizes, int n_in,
                              void* d_out, int out_size, void* d_ws, size_t ws_size,
                              hipStream_t stream) {
    const float* img = (const float*)d_in[0];
    float* out = (float*)d_out;
    dim3 block(64, 4);
    dim3 grid((IMG_W / 2) / 64, IMG_H / P / 4);   // 16 x 64 = 1024 blocks
    median5x5_strip<<<grid, block, 0, stream>>>(img, out);
}

// Round 16
// 22.328 us; speedup vs baseline: 2.4440x; 1.0080x over previous
//
#include <hip/hip_runtime.h>

constexpr int IMG_H = 2048;
constexpr int IMG_W = 2048;
constexpr int P = 4;  // output rows per thread

// compare-exchange: a=min, b=max (2 VALU)
#define CE(a, b) {                                              \
    float _mn, _mx;                                             \
    asm("v_min_f32 %0, %1, %2" : "=v"(_mn) : "v"(a), "v"(b));   \
    asm("v_max_f32 %0, %1, %2" : "=v"(_mx) : "v"(a), "v"(b));   \
    a = _mn; b = _mx;                                           \
}

// 3-element sort via VOP3 3-input ops: a=min, b=med, c=max (3 VALU)
#define SORT3(a, b, c) {                                                      \
    float _n, _d, _x;                                                         \
    asm("v_min3_f32 %0, %1, %2, %3" : "=v"(_n) : "v"(a), "v"(b), "v"(c));     \
    asm("v_med3_f32 %0, %1, %2, %3" : "=v"(_d) : "v"(a), "v"(b), "v"(c));     \
    asm("v_max3_f32 %0, %1, %2, %3" : "=v"(_x) : "v"(a), "v"(b), "v"(c));     \
    a = _n; b = _d; c = _x;                                                   \
}

__device__ __forceinline__ void sw14(float& a0, float& a1, float& a2, float& a3, float& a4,
                                     float& a5, float& a6, float& a7, float& a8, float& a9,
                                     float& a10, float& a11, float& a12, float& a13) {
    SORT3(a0, a1, a2) SORT3(a3, a4, a5) SORT3(a6, a7, a8) SORT3(a9, a10, a11) CE(a12, a13)
    SORT3(a0, a3, a6) SORT3(a0, a9, a12)
    SORT3(a2, a5, a8) SORT3(a8, a11, a13)
}
__device__ __forceinline__ void sw13(float& a0, float& a1, float& a2, float& a3, float& a4,
                                     float& a5, float& a6, float& a7, float& a8, float& a9,
                                     float& a10, float& a11, float& a12) {
    SORT3(a0, a1, a2) SORT3(a3, a4, a5) SORT3(a6, a7, a8) SORT3(a9, a10, a11)
    SORT3(a0, a3, a6) SORT3(a0, a9, a12)
    SORT3(a2, a5, a8) SORT3(a8, a11, a12)
}
__device__ __forceinline__ void sw12(float& a0, float& a1, float& a2, float& a3, float& a4,
                                     float& a5, float& a6, float& a7, float& a8, float& a9,
                                     float& a10, float& a11) {
    SORT3(a0, a1, a2) SORT3(a3, a4, a5) SORT3(a6, a7, a8) SORT3(a9, a10, a11)
    SORT3(a0, a3, a6) CE(a0, a9)
    SORT3(a2, a5, a8) CE(a8, a11)
}
__device__ __forceinline__ void sw11(float& a0, float& a1, float& a2, float& a3, float& a4,
                                     float& a5, float& a6, float& a7, float& a8, float& a9,
                                     float& a10) {
    SORT3(a0, a1, a2) SORT3(a3, a4, a5) SORT3(a6, a7, a8) CE(a9, a10)
    SORT3(a0, a3, a6) CE(a0, a9)
    SORT3(a2, a5, a8) CE(a8, a10)
}
__device__ __forceinline__ void sw10(float& a0, float& a1, float& a2, float& a3, float& a4,
                                     float& a5, float& a6, float& a7, float& a8, float& a9) {
    SORT3(a0, a1, a2) SORT3(a3, a4, a5) SORT3(a6, a7, a8)
    SORT3(a0, a3, a6) CE(a0, a9)
    SORT3(a2, a5, a8) CE(a8, a9)
}
__device__ __forceinline__ void sw9(float& a0, float& a1, float& a2, float& a3, float& a4,
                                    float& a5, float& a6, float& a7, float& a8) {
    SORT3(a0, a1, a2) SORT3(a3, a4, a5) SORT3(a6, a7, a8)
    SORT3(a0, a3, a6)
    SORT3(a2, a5, a8)
}
__device__ __forceinline__ void sw8(float& a0, float& a1, float& a2, float& a3, float& a4,
                                    float& a5, float& a6, float& a7) {
    SORT3(a0, a1, a2) SORT3(a3, a4, a5) CE(a6, a7)
    SORT3(a0, a3, a6)
    SORT3(a2, a5, a7)
}
__device__ __forceinline__ void sw7(float& a0, float& a1, float& a2, float& a3, float& a4,
                                    float& a5, float& a6) {
    SORT3(a0, a1, a2) SORT3(a3, a4, a5)
    SORT3(a0, a3, a6)
    SORT3(a2, a5, a6)
}
__device__ __forceinline__ void sw6(float& a0, float& a1, float& a2, float& a3, float& a4,
                                    float& a5) {
    SORT3(a0, a1, a2) SORT3(a3, a4, a5)
    CE(a0, a3)
    CE(a2, a5)
}

__device__ __forceinline__ float med5(float l0, float l1, float l2, float l3, float l4) {
    CE(l0, l1) CE(l2, l3)
    float a, b;
    asm("v_max_f32 %0, %1, %2" : "=v"(a) : "v"(l0), "v"(l2));
    asm("v_min_f32 %0, %1, %2" : "=v"(b) : "v"(l1), "v"(l3));
    return __builtin_amdgcn_fmed3f(a, b, l4);
}

// tail: 8 shared survivors + 5 private column values -> exact median of 25
__device__ __forceinline__ float tail5(float l1, float l2, float l3, float l4, float l5,
                                       float l6, float l7, float l8,
                                       float p0, float p1, float p2, float p3, float p4) {
    float l0 = p0;
    sw9(l0, l1, l2, l3, l4, l5, l6, l7, l8);
    l0 = p1;
    sw8(l0, l1, l2, l3, l4, l5, l6, l7);
    l0 = p2;
    sw7(l0, l1, l2, l3, l4, l5, l6);
    l0 = p3;
    sw6(l0, l1, l2, l3, l4, l5);
    l0 = p4;
    return med5(l0, l1, l2, l3, l4);
}

// shared forgetful phase over 20 elements (4 shared cols x 5 rows) -> middle 8.
__device__ __forceinline__ void shared20(float s0, float s1, float s2, float s3, float s4,
                                         float s5, float s6, float s7, float s8, float s9,
                                         float s10, float s11, float s12, float s13,
                                         float s14, float s15, float s16, float s17,
                                         float s18, float s19,
                                         float& o0, float& o1, float& o2, float& o3,
                                         float& o4, float& o5, float& o6, float& o7) {
    sw14(s0, s1, s2, s3, s4, s5, s6, s7, s8, s9, s10, s11, s12, s13);
    s0 = s14;
    sw13(s0, s1, s2, s3, s4, s5, s6, s7, s8, s9, s10, s11, s12);
    s0 = s15;
    sw12(s0, s1, s2, s3, s4, s5, s6, s7, s8, s9, s10, s11);
    s0 = s16;
    sw11(s0, s1, s2, s3, s4, s5, s6, s7, s8, s9, s10);
    s0 = s17;
    sw10(s0, s1, s2, s3, s4, s5, s6, s7, s8, s9);
    s0 = s18;
    sw9(s0, s1, s2, s3, s4, s5, s6, s7, s8);
    s0 = s19;
    o0 = s0; o1 = s1; o2 = s2; o3 = s3; o4 = s4; o5 = s5; o6 = s6; o7 = s7;
}

__device__ __forceinline__ int rowbase(int r) {
    r = (r < 0) ? -r : r;
    r = (r >= IMG_H) ? 2 * IMG_H - 2 - r : r;
    return r * IMG_W;
}

// load one window row (6 reflected columns) into named registers R0..R5
#define LOADR(R, rb) {                                        \
    const int _b = (rb);                                      \
    R##0 = img[_b + c0]; R##1 = img[_b + c1];                 \
    R##2 = img[_b + c2]; R##3 = img[_b + c3];                 \
    R##4 = img[_b + c4]; R##5 = img[_b + c5];                 \
}

// one output row: prefetch row (yy)+3 into Rf, compute median row yy from Ra..Re
#define STEP(Ra, Rb, Rc, Rd, Re, Rf, yy) {                                     \
    LOADR(Rf, rowbase((yy) + 3))                                               \
    float u0, u1, u2, u3, u4, u5, u6, u7;                                      \
    shared20(Ra##1, Ra##2, Ra##3, Ra##4, Rb##1, Rb##2, Rb##3, Rb##4,           \
             Rc##1, Rc##2, Rc##3, Rc##4, Rd##1, Rd##2, Rd##3, Rd##4,           \
             Re##1, Re##2, Re##3, Re##4, u0, u1, u2, u3, u4, u5, u6, u7);      \
    const float _mL = tail5(u0, u1, u2, u3, u4, u5, u6, u7,                    \
                            Ra##0, Rb##0, Rc##0, Rd##0, Re##0);                \
    const float _mR = tail5(u0, u1, u2, u3, u4, u5, u6, u7,                    \
                            Ra##5, Rb##5, Rc##5, Rd##5, Re##5);                \
    *reinterpret_cast<float2*>(out + (yy) * IMG_W + xL) = make_float2(_mL, _mR); \
}

// single-wave blocks: 8192 blocks stream through the CUs independently
__global__ __launch_bounds__(64) void median5x5_strip(const float* __restrict__ img,
                                                      float* __restrict__ out) {
    const int t = blockIdx.x * 64 + threadIdx.x;   // pair-column 0..1023
    const int strip = blockIdx.y;                  // 0..511
    const int y0 = strip * P;
    const int xL = 2 * t;

    // reflected column indices xL-2 .. xL+3 (constant over the strip)
    int c0 = xL - 2, c1 = xL - 1, c4 = xL + 2, c5 = xL + 3;
    c0 = (c0 < 0) ? -c0 : c0;
    c1 = (c1 < 0) ? -c1 : c1;
    c4 = (c4 >= IMG_W) ? 2 * IMG_W - 2 - c4 : c4;
    c5 = (c5 >= IMG_W) ? 2 * IMG_W - 2 - c5 : c5;
    const int c2 = xL, c3 = xL + 1;

    // sliding 5-row x 6-col register window across 6 row buffers A..F
    float A0, A1, A2, A3, A4, A5;
    float B0, B1, B2, B3, B4, B5;
    float C0, C1, C2, C3, C4, C5;
    float D0, D1, D2, D3, D4, D5;
    float E0, E1, E2, E3, E4, E5;
    float F0, F1, F2, F3, F4, F5;

    // prologue: rows y0-2 .. y0+2
    LOADR(A, rowbase(y0 - 2))
    LOADR(B, rowbase(y0 - 1))
    LOADR(C, rowbase(y0))
    LOADR(D, rowbase(y0 + 1))
    LOADR(E, rowbase(y0 + 2))

    STEP(A, B, C, D, E, F, y0 + 0)
    STEP(B, C, D, E, F, A, y0 + 1)
    STEP(C, D, E, F, A, B, y0 + 2)
    STEP(D, E, F, A, B, C, y0 + 3)
}

extern "C" void kernel_launch(void* const* d_in, const int* in_sizes, int n_in,
                              void* d_out, int out_size, void* d_ws, size_t ws_size,
                              hipStream_t stream) {
    const float* img = (const float*)d_in[0];
    float* out = (float*)d_out;
    dim3 block(64);
    dim3 grid(16, IMG_H / P);   // 16 x 512 = 8192 single-wave blocks
    median5x5_strip<<<grid, block, 0, stream>>>(img, out);
}